// Round 6
// baseline (487.666 us; speedup 1.0000x reference)
//
#include <hip/hip_runtime.h>

#define D 512
#define T 2048
#define BATCH 8
#define M_ROWS (BATCH*T)   // 16384
#define CHK 64             // chunk length
#define NCHB 32            // chunks per batch
#define NCHUNK 256         // total chunks

typedef __attribute__((ext_vector_type(8))) short short8;
typedef __attribute__((ext_vector_type(4))) float floatx4;

__device__ __forceinline__ unsigned short f2bf(float f) {
  unsigned int u = __float_as_uint(f);
  u += 0x7FFFu + ((u >> 16) & 1u);          // RNE
  return (unsigned short)(u >> 16);
}
__device__ __forceinline__ float bf2f(unsigned int h) {
  return __uint_as_float(h << 16);
}
__device__ __forceinline__ float wave_allreduce(float v) {
  #pragma unroll
  for (int m = 32; m; m >>= 1) v += __shfl_xor(v, m, 64);
  return v;
}
__device__ __forceinline__ void unpack8(uint4 r, float f[8]) {
  f[0] = bf2f(r.x & 0xffffu); f[1] = bf2f(r.x >> 16);
  f[2] = bf2f(r.y & 0xffffu); f[3] = bf2f(r.y >> 16);
  f[4] = bf2f(r.z & 0xffffu); f[5] = bf2f(r.z >> 16);
  f[6] = bf2f(r.w & 0xffffu); f[7] = bf2f(r.w >> 16);
}

// ---------------- f32 -> bf16 cast ----------------
__global__ __launch_bounds__(256) void cast_kernel(const float* __restrict__ src,
                                                   unsigned short* __restrict__ dst, int n) {
  int idx = (blockIdx.x * 256 + threadIdx.x) * 8;
  if (idx >= n) return;
  const float4* sp = (const float4*)(src + idx);
  float4 a = sp[0], b = sp[1];
  uint4 o;
  o.x = f2bf(a.x) | ((unsigned)f2bf(a.y) << 16);
  o.y = f2bf(a.z) | ((unsigned)f2bf(a.w) << 16);
  o.z = f2bf(b.x) | ((unsigned)f2bf(b.y) << 16);
  o.w = f2bf(b.z) | ((unsigned)f2bf(b.w) << 16);
  *(uint4*)(dst + idx) = o;
}

// ---------------- bf16 MFMA GEMM: C = A(MxK) * W(NxK)^T + bias ----------------
#define BM 128
#define BN 128
#define BK 32

template<bool OUT_BF16>
__global__ __launch_bounds__(256) void gemm_nt(
    const unsigned short* __restrict__ A, const unsigned short* __restrict__ Bw,
    const float* __restrict__ bias, void* __restrict__ Cout, int M, int N, int K)
{
  __shared__ __align__(16) unsigned short As[BM * BK];
  __shared__ __align__(16) unsigned short Bs[BN * BK];
  int tid  = threadIdx.x;
  int lane = tid & 63;
  int wave = tid >> 6;
  int waveM = (wave >> 1) * 64;
  int waveN = (wave & 1) * 64;
  int lrow = lane & 15;
  int quad = lane >> 4;

  floatx4 acc[4][4];
  #pragma unroll
  for (int a_ = 0; a_ < 4; ++a_)
    #pragma unroll
    for (int b_ = 0; b_ < 4; ++b_) acc[a_][b_] = (floatx4){0.f, 0.f, 0.f, 0.f};

  const unsigned short* Ap = A  + (size_t)(blockIdx.y * BM) * K;
  const unsigned short* Bp = Bw + (size_t)(blockIdx.x * BN) * K;
  int r0 = tid >> 2;
  int c0 = (tid & 3) * 8;

  for (int k0 = 0; k0 < K; k0 += BK) {
    __syncthreads();
    *(uint4*)&As[r0 * BK + c0]        = *(const uint4*)&Ap[(size_t)r0 * K + k0 + c0];
    *(uint4*)&As[(r0 + 64) * BK + c0] = *(const uint4*)&Ap[(size_t)(r0 + 64) * K + k0 + c0];
    *(uint4*)&Bs[r0 * BK + c0]        = *(const uint4*)&Bp[(size_t)r0 * K + k0 + c0];
    *(uint4*)&Bs[(r0 + 64) * BK + c0] = *(const uint4*)&Bp[(size_t)(r0 + 64) * K + k0 + c0];
    __syncthreads();
    short8 af[4], bf[4];
    #pragma unroll
    for (int mt = 0; mt < 4; ++mt)
      af[mt] = *(const short8*)&As[(waveM + mt * 16 + lrow) * BK + quad * 8];
    #pragma unroll
    for (int nt = 0; nt < 4; ++nt)
      bf[nt] = *(const short8*)&Bs[(waveN + nt * 16 + lrow) * BK + quad * 8];
    #pragma unroll
    for (int mt = 0; mt < 4; ++mt)
      #pragma unroll
      for (int nt = 0; nt < 4; ++nt)
        acc[mt][nt] = __builtin_amdgcn_mfma_f32_16x16x32_bf16(af[mt], bf[nt], acc[mt][nt], 0, 0, 0);
  }

  int cm = blockIdx.y * BM + waveM;
  int cn = blockIdx.x * BN + waveN;
  #pragma unroll
  for (int nt = 0; nt < 4; ++nt) {
    int col = cn + nt * 16 + lrow;
    float bv = bias[col];
    #pragma unroll
    for (int mt = 0; mt < 4; ++mt) {
      #pragma unroll
      for (int r = 0; r < 4; ++r) {
        int row = cm + mt * 16 + quad * 4 + r;
        float v = acc[mt][nt][r] + bv;
        if (OUT_BF16) ((unsigned short*)Cout)[(size_t)row * N + col] = f2bf(v);
        else          ((float*)Cout)[(size_t)row * N + col] = v;
      }
    }
  }
}

// ---------------- K l2-normalize (in place) + Beta ----------------
__global__ __launch_bounds__(256) void norm_beta_kernel(
    unsigned short* __restrict__ Kb, const float* __restrict__ Wbeta,
    const float* __restrict__ bbeta, float* __restrict__ Beta)
{
  int w = blockIdx.x * 4 + (threadIdx.x >> 6);
  int lane = threadIdx.x & 63;
  unsigned short* kp = Kb + (size_t)w * D + lane * 8;
  uint4 raw = *(uint4*)kp;
  float kv[8]; unpack8(raw, kv);
  float ss = 0.f;
  #pragma unroll
  for (int m = 0; m < 8; ++m) ss += kv[m] * kv[m];
  ss = wave_allreduce(ss);
  float inv = 1.0f / fmaxf(sqrtf(ss), 1e-12f);
  const float* wb = Wbeta + lane * 8;
  float dotp = 0.f;
  #pragma unroll
  for (int m = 0; m < 8; ++m) { kv[m] *= inv; dotp += kv[m] * wb[m]; }
  uint4 o;
  o.x = f2bf(kv[0]) | ((unsigned)f2bf(kv[1]) << 16);
  o.y = f2bf(kv[2]) | ((unsigned)f2bf(kv[3]) << 16);
  o.z = f2bf(kv[4]) | ((unsigned)f2bf(kv[5]) << 16);
  o.w = f2bf(kv[6]) | ((unsigned)f2bf(kv[7]) << 16);
  *(uint4*)kp = o;
  dotp = wave_allreduce(dotp);
  if (lane == 0) Beta[w] = 1.0f / (1.0f + expf(-(dotp + bbeta[0])));
}

// ---------------- per-chunk MFMA-identity transpose: XT[cb][dd][t] = X[cb*64+t][dd] ----------------
// C = sum_k delta(m,k)*B[n,k] = B^T tile. No LDS, coalesced b128 reads, L2-merged stores.
__global__ __launch_bounds__(256) void transpose_kv(
    const unsigned short* __restrict__ Kb, const unsigned short* __restrict__ Vb,
    unsigned short* __restrict__ KT, unsigned short* __restrict__ VT)
{
  int cb = blockIdx.x & 255;
  const unsigned short* src = (blockIdx.x < 256 ? Kb : Vb) + (size_t)cb * 64 * 512;
  unsigned short* dst = (blockIdx.x < 256 ? KT : VT) + (size_t)cb * 32768;
  int lane = threadIdx.x & 63, w = threadIdx.x >> 6;
  int lr = lane & 15, quad = lane >> 4;
  short8 a0, a1;
  #pragma unroll
  for (int j = 0; j < 8; ++j) {
    a0[j] = (quad == (lr >> 3)     && j == (lr & 7)) ? (short)0x3F80 : (short)0;
    a1[j] = (quad == 2 + (lr >> 3) && j == (lr & 7)) ? (short)0x3F80 : (short)0;
  }
  int t0 = w * 16;
  #pragma unroll 4
  for (int dk0 = 0; dk0 < 16; ++dk0) {
    short8 b = *(const short8*)&src[(size_t)(t0 + lr) * 512 + dk0 * 32 + quad * 8];
    floatx4 z = (floatx4){0.f,0.f,0.f,0.f};
    floatx4 c0 = __builtin_amdgcn_mfma_f32_16x16x32_bf16(a0, b, z, 0, 0, 0);
    floatx4 c1 = __builtin_amdgcn_mfma_f32_16x16x32_bf16(a1, b, z, 0, 0, 0);
    #pragma unroll
    for (int r = 0; r < 4; ++r) {
      dst[(dk0 * 32 +      quad * 4 + r) * 64 + t0 + lr] = f2bf(c0[r]);
      dst[(dk0 * 32 + 16 + quad * 4 + r) * 64 + t0 + lr] = f2bf(c1[r]);
    }
  }
}

// ---------------- per-chunk Gram: A = strict_tril(beta_t * K K^T) f32, Ms = tril(Q K^T) bf16 ----------------
__global__ __launch_bounds__(256) void gram_kernel(
    const unsigned short* __restrict__ Qb, const unsigned short* __restrict__ Kb,
    const float* __restrict__ Beta, float* __restrict__ Abuf,
    unsigned short* __restrict__ Msb)
{
  int cb = blockIdx.x, tid = threadIdx.x, lane = tid & 63, w = tid >> 6;
  int lr = lane & 15, quad = lane >> 4;
  const unsigned short* kc = Kb + (size_t)cb * 64 * 512;
  const unsigned short* qc = Qb + (size_t)cb * 64 * 512;
  floatx4 accK[4], accQ[4];
  #pragma unroll
  for (int nt = 0; nt < 4; ++nt) { accK[nt] = (floatx4){0,0,0,0}; accQ[nt] = (floatx4){0,0,0,0}; }
  // rolling 1-step prefetch
  short8 ak = *(const short8*)&kc[(w * 16 + lr) * 512 + quad * 8];
  short8 aq = *(const short8*)&qc[(w * 16 + lr) * 512 + quad * 8];
  short8 bk[4];
  #pragma unroll
  for (int nt = 0; nt < 4; ++nt)
    bk[nt] = *(const short8*)&kc[(nt * 16 + lr) * 512 + quad * 8];
  #pragma unroll
  for (int ks = 0; ks < 16; ++ks) {
    short8 akn, aqn, bkn[4];
    if (ks < 15) {
      int off = (ks + 1) * 32 + quad * 8;
      akn = *(const short8*)&kc[(w * 16 + lr) * 512 + off];
      aqn = *(const short8*)&qc[(w * 16 + lr) * 512 + off];
      #pragma unroll
      for (int nt = 0; nt < 4; ++nt)
        bkn[nt] = *(const short8*)&kc[(nt * 16 + lr) * 512 + off];
    }
    #pragma unroll
    for (int nt = 0; nt < 4; ++nt) {
      accK[nt] = __builtin_amdgcn_mfma_f32_16x16x32_bf16(ak, bk[nt], accK[nt], 0, 0, 0);
      accQ[nt] = __builtin_amdgcn_mfma_f32_16x16x32_bf16(aq, bk[nt], accQ[nt], 0, 0, 0);
    }
    if (ks < 15) {
      ak = akn; aq = aqn;
      #pragma unroll
      for (int nt = 0; nt < 4; ++nt) bk[nt] = bkn[nt];
    }
  }
  #pragma unroll
  for (int nt = 0; nt < 4; ++nt)
    #pragma unroll
    for (int r = 0; r < 4; ++r) {
      int t = w * 16 + quad * 4 + r;
      int j = nt * 16 + lr;
      float bt = Beta[cb * 64 + t];
      Abuf[(size_t)cb * 4096 + t * 64 + j] = (j < t) ? bt * accK[nt][r] : 0.f;
      Msb[(size_t)cb * 4096 + t * 64 + j]  = f2bf((j <= t) ? accQ[nt][r] : 0.f);
    }
}

// ---------------- Tinv = (I+A)^{-1}: 1 wave per block, lane owns column `lane` ----------------
__global__ __launch_bounds__(64) void tinv_kernel(
    const float* __restrict__ Abuf, const float* __restrict__ Beta,
    unsigned short* __restrict__ Tib)
{
  __shared__ float XT[64 * 68];
  int lane = threadIdx.x;
  int cb = blockIdx.x;
  float bl = Beta[cb * 64 + lane];
  const float* Ab = Abuf + (size_t)cb * 4096;
  unsigned short* To = Tib + (size_t)cb * 4096;
  float* Xr = XT + lane * 68;
  #pragma unroll
  for (int j = 0; j < 68; j += 4) *(float4*)&Xr[j] = (float4){0.f,0.f,0.f,0.f};
  for (int t = 0; t < 64; ++t) {
    const float* Ar = Ab + t * 64;
    float p0 = 0.f, p1 = 0.f, p2 = 0.f, p3 = 0.f;
    for (int jb = 0; jb < t; jb += 4) {
      float4 xv = *(const float4*)&Xr[jb];
      float4 av = *(const float4*)&Ar[jb];
      p0 = fmaf(av.x, xv.x, p0); p1 = fmaf(av.y, xv.y, p1);
      p2 = fmaf(av.z, xv.z, p2); p3 = fmaf(av.w, xv.w, p3);
    }
    float y = ((lane == t) ? 1.f : 0.f) - (p0 + p1) - (p2 + p3);
    Xr[t] = y;
    To[t * 64 + lane] = f2bf(y * bl);
  }
}

// ---------------- Wneg = -Tinvbeta*K, Ubar = Tinvbeta*V; LDS-staged coalesced out ----------------
__global__ __launch_bounds__(256) void wu_kernel(
    const unsigned short* __restrict__ Tib, const unsigned short* __restrict__ KT,
    const unsigned short* __restrict__ VT, unsigned short* __restrict__ Wneg,
    unsigned short* __restrict__ Ubar)
{
  __shared__ __align__(16) unsigned short WL[64 * 512];   // 64 KB
  __shared__ __align__(16) unsigned short UL[64 * 512];   // 64 KB
  int cb = blockIdx.x, tid = threadIdx.x, lane = tid & 63, w = tid >> 6;
  int lr = lane & 15, quad = lane >> 4;
  short8 af0 = *(const short8*)&Tib[(size_t)cb * 4096 + (w * 16 + lr) * 64 + quad * 8];
  short8 af1 = *(const short8*)&Tib[(size_t)cb * 4096 + (w * 16 + lr) * 64 + 32 + quad * 8];
  const unsigned short* ktc = KT + (size_t)cb * 32768 + lr * 64 + quad * 8;
  const unsigned short* vtc = VT + (size_t)cb * 32768 + lr * 64 + quad * 8;
  int tbase = w * 16 + quad * 4;
  #pragma unroll 4
  for (int nt = 0; nt < 32; ++nt) {
    short8 bk0 = *(const short8*)(ktc + nt * 1024);
    short8 bk1 = *(const short8*)(ktc + nt * 1024 + 32);
    short8 bv0 = *(const short8*)(vtc + nt * 1024);
    short8 bv1 = *(const short8*)(vtc + nt * 1024 + 32);
    floatx4 z = (floatx4){0.f,0.f,0.f,0.f};
    floatx4 aw = __builtin_amdgcn_mfma_f32_16x16x32_bf16(af0, bk0, z, 0, 0, 0);
    aw = __builtin_amdgcn_mfma_f32_16x16x32_bf16(af1, bk1, aw, 0, 0, 0);
    floatx4 au = __builtin_amdgcn_mfma_f32_16x16x32_bf16(af0, bv0, z, 0, 0, 0);
    au = __builtin_amdgcn_mfma_f32_16x16x32_bf16(af1, bv1, au, 0, 0, 0);
    int bi = nt * 2 + (lr >> 3);
    int lo = lr & 7;
    #pragma unroll
    for (int r = 0; r < 4; ++r) {
      int tt = tbase + r;
      int bis = bi ^ (tt & 7);
      WL[tt * 512 + bis * 8 + lo] = f2bf(-aw[r]);
      UL[tt * 512 + bis * 8 + lo] = f2bf(au[r]);
    }
  }
  __syncthreads();
  unsigned short* wd = Wneg + (size_t)cb * 32768;
  unsigned short* ud = Ubar + (size_t)cb * 32768;
  #pragma unroll
  for (int it = 0; it < 16; ++it) {
    int e = it * 2048 + tid * 8;
    int row = e >> 9, col = e & 511;
    int bis = (col >> 3) ^ (row & 7);
    *(uint4*)&wd[e] = *(const uint4*)&WL[row * 512 + bis * 8];
    *(uint4*)&ud[e] = *(const uint4*)&UL[row * 512 + bis * 8];
  }
}

// ---------------- sequential chunk scan: 1024 threads, 16 waves, split-K/4 phase1 ----------------
// per chunk: U = Ubar + Wneg*S^T ; O = Q*S^T + Ms*U ; S += U^T*K
__global__ __launch_bounds__(1024) void seq_kernel(
    const unsigned short* __restrict__ Wneg, const unsigned short* __restrict__ Qb,
    const unsigned short* __restrict__ Ubar, const unsigned short* __restrict__ Msb,
    const unsigned short* __restrict__ KT, unsigned short* __restrict__ Ob)
{
  __shared__ __align__(16) unsigned short Sb[16 * 520];   // S^T [v][dk], 16.6 KB
  __shared__ __align__(16) float DUp[64 * 64];            // [t][v*4+kg], 16 KB
  __shared__ __align__(16) float DOp[64 * 64];            // 16 KB
  __shared__ __align__(16) unsigned short Ut[16 * 72];    // U^T [v][t], 2.3 KB
  int blk = blockIdx.x;
  int b = blk >> 5, vs = blk & 31;
  int vg0 = vs * 16;
  int tid = threadIdx.x, lane = tid & 63, wave = tid >> 6;
  int lr = lane & 15, quad = lane >> 4;
  int kg = wave & 3;        // K-group for phase1 (k = kg*128..+128)
  int tm = wave >> 2;       // t-tile for phase1 (rows tm*16..+16)
  int ct = tid >> 4, cv = tid & 15;   // combine-thread mapping: (t, v)

  // wave owns dk-tiles {wave*32, wave*32+16} of S^T (rows v, cols dk)
  floatx4 sacc[2];
  sacc[0] = (floatx4){0.f,0.f,0.f,0.f};
  sacc[1] = (floatx4){0.f,0.f,0.f,0.f};

  int cb0 = b * NCHB;
  for (int ch = 0; ch < NCHB; ++ch) {
    int cb = cb0 + ch;
    size_t tokb = (size_t)cb * 64;
    // ---- early global loads (land before their phase) ----
    short8 wnf[4], qff[4];
    {
      const unsigned short* wr = Wneg + (tokb + tm * 16 + lr) * 512 + kg * 128 + quad * 8;
      const unsigned short* qr = Qb   + (tokb + tm * 16 + lr) * 512 + kg * 128 + quad * 8;
      #pragma unroll
      for (int ks = 0; ks < 4; ++ks) {
        wnf[ks] = *(const short8*)(wr + ks * 32);
        qff[ks] = *(const short8*)(qr + ks * 32);
      }
    }
    unsigned short ubv = Ubar[(tokb + ct) * 512 + vg0 + cv];
    short8 ktf[2][2];
    {
      const unsigned short* kr = KT + (size_t)cb * 32768 + (wave * 32 + lr) * 64 + quad * 8;
      ktf[0][0] = *(const short8*)(kr);
      ktf[0][1] = *(const short8*)(kr + 32);
      ktf[1][0] = *(const short8*)(kr + 16 * 64);
      ktf[1][1] = *(const short8*)(kr + 16 * 64 + 32);
    }
    short8 msf0, msf1;
    if (kg == 0) {
      const unsigned short* mr = Msb + (size_t)cb * 4096 + (tm * 16 + lr) * 64 + quad * 8;
      msf0 = *(const short8*)(mr);
      msf1 = *(const short8*)(mr + 32);
    }
    // ---- phase 0: stage S^T into LDS ----
    #pragma unroll
    for (int s = 0; s < 2; ++s)
      #pragma unroll
      for (int r = 0; r < 4; ++r)
        Sb[(quad * 4 + r) * 520 + wave * 32 + s * 16 + lr] = f2bf(sacc[s][r]);
    __syncthreads();
    // ---- phase 1: partial U and Q*S^T over K-slice kg ----
    floatx4 du = (floatx4){0.f,0.f,0.f,0.f};
    floatx4 dq = (floatx4){0.f,0.f,0.f,0.f};
    #pragma unroll
    for (int ks = 0; ks < 4; ++ks) {
      short8 sb = *(const short8*)&Sb[lr * 520 + kg * 128 + ks * 32 + quad * 8];
      du = __builtin_amdgcn_mfma_f32_16x16x32_bf16(wnf[ks], sb, du, 0, 0, 0);
      dq = __builtin_amdgcn_mfma_f32_16x16x32_bf16(qff[ks], sb, dq, 0, 0, 0);
    }
    #pragma unroll
    for (int r = 0; r < 4; ++r) {
      int t = tm * 16 + quad * 4 + r;
      DUp[t * 64 + lr * 4 + kg] = du[r];
      DOp[t * 64 + lr * 4 + kg] = dq[r];
    }
    __syncthreads();
    // ---- phase 1b: combine partials -> U^T (bf16) ----
    {
      float4 p = *(const float4*)&DUp[ct * 64 + cv * 4];
      float uval = (p.x + p.y) + (p.z + p.w) + bf2f(ubv);
      Ut[cv * 72 + ct] = f2bf(uval);
    }
    __syncthreads();
    // ---- phase 2: S += U^T*K ; O = sum(DOp) + Ms*U ----
    short8 a20 = *(const short8*)&Ut[lr * 72 + quad * 8];
    short8 a21 = *(const short8*)&Ut[lr * 72 + 32 + quad * 8];
    #pragma unroll
    for (int s = 0; s < 2; ++s) {
      sacc[s] = __builtin_amdgcn_mfma_f32_16x16x32_bf16(a20, ktf[s][0], sacc[s], 0, 0, 0);
      sacc[s] = __builtin_amdgcn_mfma_f32_16x16x32_bf16(a21, ktf[s][1], sacc[s], 0, 0, 0);
    }
    if (kg == 0) {
      floatx4 oo;
      #pragma unroll
      for (int r = 0; r < 4; ++r) {
        int t = tm * 16 + quad * 4 + r;
        float4 p = *(const float4*)&DOp[t * 64 + lr * 4];
        oo[r] = (p.x + p.y) + (p.z + p.w);
      }
      oo = __builtin_amdgcn_mfma_f32_16x16x32_bf16(msf0, a20, oo, 0, 0, 0);
      oo = __builtin_amdgcn_mfma_f32_16x16x32_bf16(msf1, a21, oo, 0, 0, 0);
      unsigned short* ob = Ob + (tokb + tm * 16 + quad * 4) * 512 + vg0 + lr;
      #pragma unroll
      for (int r = 0; r < 4; ++r) ob[(size_t)r * 512] = f2bf(oo[r]);
    }
    // next phase0 writes Sb (last read before barrier 2) — the loop's first
    // __syncthreads() also separates phase2's DOp/Ut reads from next phase1/1b writes.
  }
}

extern "C" void kernel_launch(void* const* d_in, const int* in_sizes, int n_in,
                              void* d_out, int out_size, void* d_ws, size_t ws_size,
                              hipStream_t stream) {
  const float* x     = (const float*)d_in[0];
  const float* Wq    = (const float*)d_in[1];
  const float* bq    = (const float*)d_in[2];
  const float* Wk    = (const float*)d_in[3];
  const float* bk    = (const float*)d_in[4];
  const float* Wv    = (const float*)d_in[5];
  const float* bv    = (const float*)d_in[6];
  const float* Wbeta = (const float*)d_in[7];
  const float* bbeta = (const float*)d_in[8];
  const float* Wo    = (const float*)d_in[9];
  const float* bo    = (const float*)d_in[10];

  const size_t NE = (size_t)M_ROWS * D;   // 8,388,608
  const size_t DD = (size_t)D * D;
  unsigned short* Qb  = (unsigned short*)d_ws;
  unsigned short* Kb  = Qb + NE;          // later: Ubar
  unsigned short* Vb  = Kb + NE;          // later: O
  unsigned short* Xb  = Vb + NE;          // x bf16; later: Wneg
  unsigned short* Wqb = Xb + NE;
  unsigned short* Wkb = Wqb + DD;
  unsigned short* Wvb = Wkb + DD;
  unsigned short* Wob = Wvb + DD;
  float* Beta = (float*)(Wob + DD);                        // 16384 f32
  unsigned short* KT  = (unsigned short*)(Beta + M_ROWS);  // NE shorts
  float* Abuf = (float*)(KT + NE);                         // 256*4096 f32
  unsigned short* Msb = (unsigned short*)(Abuf + (size_t)NCHUNK * 4096);
  unsigned short* Tib = Msb + (size_t)NCHUNK * 4096;
  unsigned short* VT  = Tib + (size_t)NCHUNK * 4096;       // NE shorts; total ~106 MB

  cast_kernel<<<(int)(NE / 2048), 256, 0, stream>>>(x, Xb, (int)NE);
  cast_kernel<<<(int)(DD / 2048), 256, 0, stream>>>(Wq, Wqb, (int)DD);
  cast_kernel<<<(int)(DD / 2048), 256, 0, stream>>>(Wk, Wkb, (int)DD);
  cast_kernel<<<(int)(DD / 2048), 256, 0, stream>>>(Wv, Wvb, (int)DD);
  cast_kernel<<<(int)(DD / 2048), 256, 0, stream>>>(Wo, Wob, (int)DD);

  dim3 gg(D / BN, M_ROWS / BM);  // (4, 128)
  gemm_nt<true><<<gg, 256, 0, stream>>>(Xb, Wqb, bq, Qb, M_ROWS, D, D);
  gemm_nt<true><<<gg, 256, 0, stream>>>(Xb, Wkb, bk, Kb, M_ROWS, D, D);
  gemm_nt<true><<<gg, 256, 0, stream>>>(Xb, Wvb, bv, Vb, M_ROWS, D, D);

  norm_beta_kernel<<<M_ROWS / 4, 256, 0, stream>>>(Kb, Wbeta, bbeta, Beta);

  transpose_kv<<<2 * NCHUNK, 256, 0, stream>>>(Kb, Vb, KT, VT);
  gram_kernel<<<NCHUNK, 256, 0, stream>>>(Qb, Kb, Beta, Abuf, Msb);
  tinv_kernel<<<NCHUNK, 64, 0, stream>>>(Abuf, Beta, Tib);
  wu_kernel<<<NCHUNK, 256, 0, stream>>>(Tib, KT, VT, /*Wneg=*/Xb, /*Ubar=*/Kb);

  seq_kernel<<<NCHUNK, 1024, 0, stream>>>(/*Wneg=*/Xb, Qb, /*Ubar=*/Kb, Msb, KT, /*O=*/Vb);

  gemm_nt<false><<<gg, 256, 0, stream>>>(Vb, Wob, bo, (float*)d_out, M_ROWS, D, D);
}